// Round 8
// baseline (926.058 us; speedup 1.0000x reference)
//
#include <hip/hip_runtime.h>

typedef unsigned short u16;
typedef __attribute__((ext_vector_type(4))) float f4;
typedef __attribute__((ext_vector_type(8))) short s8v;      // bf16x8 MFMA operand
typedef __attribute__((ext_vector_type(8))) unsigned short u16x8;
typedef __attribute__((ext_vector_type(4))) unsigned short u16x4;

#define B_   4
#define S_   4096
#define D_   2048
#define M_   (B_ * S_)     // 16384
#define K_   D_            // 2048
#define N3_  (3 * D_)      // 6144
#define CCH  128           // scan chunks
#define LCH  32            // chunk length
#define NTK  32            // K_ / 64 K-tiles

__device__ __forceinline__ u16 f2bf(float f) {
  unsigned u = __float_as_uint(f);
  u += 0x7FFF + ((u >> 16) & 1);   // RNE
  return (u16)(u >> 16);
}
__device__ __forceinline__ float bf2f(u16 h) {
  return __uint_as_float(((unsigned)h) << 16);
}
__device__ __forceinline__ float sigm(float z) {
  return 1.0f / (1.0f + __expf(-z));
}

// ---------------- fp32 -> bf16 elementwise (x) ----------------
__global__ void k_cvt(const float* __restrict__ src, u16* __restrict__ dst, int n4) {
  int i = blockIdx.x * 256 + threadIdx.x;
  if (i >= n4) return;
  f4 v = *(const f4*)(src + (size_t)i * 4);
  u16x4 o;
  o[0] = f2bf(v[0]); o[1] = f2bf(v[1]); o[2] = f2bf(v[2]); o[3] = f2bf(v[3]);
  *(u16x4*)(dst + (size_t)i * 4) = o;
}

// ---------------- fp32 [2048][2048] -> bf16 transpose ----------------
__global__ void k_tcvt(const float* __restrict__ src, u16* __restrict__ dst) {
  __shared__ float tile[32][33];
  int tx = threadIdx.x & 31, ty = threadIdx.x >> 5;
  int c0 = blockIdx.x * 32, r0 = blockIdx.y * 32;
#pragma unroll
  for (int j = 0; j < 32; j += 8)
    tile[ty + j][tx] = src[(size_t)(r0 + ty + j) * 2048 + c0 + tx];
  __syncthreads();
#pragma unroll
  for (int j = 0; j < 32; j += 8)
    dst[(size_t)(c0 + ty + j) * 2048 + r0 + tx] = f2bf(tile[tx][ty + j]);
}

// ---------------- persistent 256x256 8-phase bf16 GEMM (XCD-clustered) ------
// Grid = 256 (1/CU). Step t: block (xcd=bid&7, cu=bid>>3) takes tile
// seq = t*32+cu decoded (nsb=seq>>6, mm=(seq>>3)&7, nn=seq&7) ->
// tile_m=(xcd*8+mm)*256, tile_n=(nsb*8+nn)*256 : the 32 co-resident tiles per
// XCD form a 4m x 8n window (hot set ~768 KB << 4 MiB L2; R7-verified).
// Seamless cross-tile K-loop: the staging wrap (st&31 -> K-tiles 0,1) pulls
// from the NEXT tile's pointers during the last K-iteration (R6-verified
// ledger). Epilogue in spare 32 KiB LDS: no vmcnt drain, staging overlaps.
__global__ void __launch_bounds__(512, 2)
k_gemm256(const u16* __restrict__ A, const u16* __restrict__ BT, int N, int mode,
          int tpb,
          u16* __restrict__ o_inp, u16* __restrict__ o_dec, u16* __restrict__ o_gate,
          const float* __restrict__ b_in, const float* __restrict__ b_dec,
          const float* __restrict__ b_gate, const float* __restrict__ dbias,
          float* __restrict__ o_f, const float* __restrict__ b_out) {
  extern __shared__ u16 smem[];
  u16* const Asb[2] = { smem,         smem + 16384 };
  u16* const Bsb[2] = { smem + 32768, smem + 49152 };
  u16* const spare  = smem + 65536;                 // byte 131072, 32 KiB

  const int xcd = blockIdx.x & 7, cu = blockIdx.x >> 3;
  auto DEC = [&](int seq, int& tm, int& tn) {
    int nsb = seq >> 6, rem = seq & 63;
    tm = ((xcd << 3) + (rem >> 3)) << 8;
    tn = ((nsb << 3) + (rem & 7)) << 8;
  };

  const int tid = threadIdx.x;
  const int wave = tid >> 6, lane = tid & 63;
  const int wm = (wave >> 2) << 7;              // 0 or 128
  const int wn = (wave & 3) << 6;               // 0,64,128,192
  const int l15 = lane & 15, lhi = lane >> 4;
  const int srow = tid >> 3, sslot = tid & 7;   // staging: row-in-chunk, 16B slot

  f4 acc[8][4];
#pragma unroll
  for (int m = 0; m < 8; ++m)
#pragma unroll
    for (int n = 0; n < 4; ++n)
#pragma unroll
      for (int r = 0; r < 4; ++r) acc[m][n][r] = 0.0f;

  s8v afr2[2][2][2];   // A fragments [set][mi][kk] — set alternates per phase
  s8v bfr[2][4];       // B fragments [kk][n] — refreshed at q3 tails

  auto STAGE = [&](const u16* __restrict__ G, int grow0, u16* L, int c, int k0) {
    int r = (c << 6) + srow;
    int sc = (sslot ^ (r & 7)) << 3;            // pre-swizzled source column
    __builtin_amdgcn_global_load_lds(
        (const __attribute__((address_space(1))) unsigned int*)(G + (size_t)(grow0 + r) * K_ + k0 + sc),
        (__attribute__((address_space(3))) unsigned int*)(L + (((c << 6) + (wave << 3)) << 6)),
        16, 0, 0);
  };

  // ---- one-time prologue for tile at step 0 ----
  {
    int tm0, tn0; DEC(cu, tm0, tn0);
#pragma unroll
    for (int c = 0; c < 4; ++c) STAGE(A, tm0, Asb[0], c, 0);
#pragma unroll
    for (int c = 0; c < 4; ++c) STAGE(BT, tn0, Bsb[0], c, 0);
#pragma unroll
    for (int c = 0; c < 4; ++c) STAGE(BT, tn0, Bsb[1], c, 64);
    STAGE(A, tm0, Asb[1], 0, 64);
    STAGE(A, tm0, Asb[1], 2, 64);
    asm volatile("s_waitcnt vmcnt(6)" ::: "memory");   // K-tile 0 landed
    __builtin_amdgcn_s_barrier();
#pragma unroll
    for (int kk = 0; kk < 2; ++kk)
#pragma unroll
      for (int mi = 0; mi < 2; ++mi) {
        int r = wm + (mi << 4) + l15;
        afr2[0][mi][kk] = *(const s8v*)(Asb[0] + (r << 6) + ((((kk << 2) + lhi) ^ (r & 7)) << 3));
      }
#pragma unroll
    for (int kk = 0; kk < 2; ++kk)
#pragma unroll
      for (int n = 0; n < 4; ++n) {
        int r = wn + (n << 4) + l15;
        bfr[kk][n] = *(const s8v*)(Bsb[0] + (r << 6) + ((((kk << 2) + lhi) ^ (r & 7)) << 3));
      }
  }

#pragma unroll 1
  for (int t = 0; t < tpb; ++t) {
    int tile_m, tile_n; DEC(t * 32 + cu, tile_m, tile_n);
    int tm_nx, tn_nx;
    DEC((t + 1 < tpb) ? (t + 1) * 32 + cu : t * 32 + cu, tm_nx, tn_nx);  // last: dead self-restage

#pragma unroll 1
    for (int it = 0; it < NTK / 2; ++it) {
      const int t0 = it << 1;
      const int last_it = (it == NTK / 2 - 1);
#pragma unroll
      for (int p = 0; p < 8; ++p) {
        const int toff[8] = {1, 2, 2, 2, 2, 3, 3, 3};   // staged tile = t0 + toff
        const int sopA[8] = {1, 0, 0, 1, 1, 0, 0, 1};   // 1 = stage A chunks, 0 = B
        const int sc0[8]  = {1, 0, 2, 0, 1, 0, 2, 0};
        const int sc1f[8] = {3, 1, 3, 2, 3, 1, 3, 2};
        const int q = p & 3;

        // ---- stage: 2 chunks of a future K-tile (next tile's if wrapping) ----
        {
          const int st = (t0 + toff[p]) & (NTK - 1);
          const int k0s = st << 6;
          const int nxt = last_it && p >= 1;             // wrapped -> next tile
          u16* const Ad = Asb[st & 1];
          u16* const Bd = Bsb[st & 1];
          if (sopA[p]) {
            const int gm = nxt ? tm_nx : tile_m;
            STAGE(A, gm, Ad, sc0[p], k0s); STAGE(A, gm, Ad, sc1f[p], k0s);
          } else {
            const int gb = nxt ? tn_nx : tile_n;
            STAGE(BT, gb, Bd, sc0[p], k0s); STAGE(BT, gb, Bd, sc1f[p], k0s);
          }
        }
        if (q == 3) {
          asm volatile("s_waitcnt vmcnt(6)" ::: "memory");  // next buf's 8 loads landed
          __builtin_amdgcn_sched_barrier(0);
        }
        __builtin_amdgcn_s_barrier();

        // ---- read-ahead: A fragments for phase p+1 ----
        {
          const int pn = p + 1;
          const int qn = pn & 3, bn = (pn >> 2) & 1, as = pn & 1;
          u16* const Anx = Asb[bn];
#pragma unroll
          for (int kk = 0; kk < 2; ++kk)
#pragma unroll
            for (int mi = 0; mi < 2; ++mi) {
              int r = wm + ((qn * 2 + mi) << 4) + l15;
              afr2[as][mi][kk] = *(const s8v*)(Anx + (r << 6) + ((((kk << 2) + lhi) ^ (r & 7)) << 3));
            }
        }

        __builtin_amdgcn_s_setprio(1);
#pragma unroll
        for (int kk = 0; kk < 2; ++kk)
#pragma unroll
          for (int mi = 0; mi < 2; ++mi)
#pragma unroll
            for (int n = 0; n < 4; ++n)
              acc[q * 2 + mi][n] =
                  __builtin_amdgcn_mfma_f32_16x16x32_bf16(afr2[p & 1][mi][kk], bfr[kk][n],
                                                          acc[q * 2 + mi][n], 0, 0, 0);
        __builtin_amdgcn_s_setprio(0);

        // ---- q3 tail: B fragments for the next 4 phases (next tile's at p7 of last it) ----
        if (q == 3) {
          const int bn = ((p + 1) >> 2) & 1;
          u16* const Bnx = Bsb[bn];
#pragma unroll
          for (int kk = 0; kk < 2; ++kk)
#pragma unroll
            for (int n = 0; n < 4; ++n) {
              int r = wn + (n << 4) + l15;
              bfr[kk][n] = *(const s8v*)(Bnx + (r << 6) + ((((kk << 2) + lhi) ^ (r & 7)) << 3));
            }
        }
        __builtin_amdgcn_s_barrier();
      }
    }

    // ---- epilogue in spare LDS (staging buffers untouched; loads keep flying) ----
    if (mode == 0) {
      const int selb = tile_n >> 11;
      const int dbase = tile_n & 2047;
      u16* const dst = (selb == 0) ? o_inp : (selb == 1) ? o_dec : o_gate;
      float bias[4];
#pragma unroll
      for (int n = 0; n < 4; ++n) {
        int d = dbase + wn + (n << 4) + l15;
        bias[n] = (selb == 0) ? b_in[d] : (selb == 1) ? (b_dec[d] + dbias[d]) : b_gate[d];
      }
      const int rr = tid >> 5, sl = tid & 31;
#pragma unroll
      for (int sw = 0; sw < 4; ++sw) {
        if ((wm >> 7) == (sw >> 1)) {
          const int mb = (sw & 1) << 2;
#pragma unroll
          for (int mm = 0; mm < 4; ++mm) {
#pragma unroll
            for (int n = 0; n < 4; ++n)
#pragma unroll
              for (int r = 0; r < 4; ++r) {
                int lr = (mm << 4) + (lhi << 2) + r;           // 0..63 in sweep
                int lcol = wn + (n << 4) + l15;
                float z = acc[mb + mm][n][r] + bias[n];
                float v = (selb == 0) ? z * sigm(z) : sigm(z);
                spare[(lr << 8) + (((lcol >> 3) ^ (lr & 7)) << 3) + (lcol & 7)] = f2bf(v);
              }
          }
        }
        asm volatile("s_waitcnt lgkmcnt(0)" ::: "memory");
        __builtin_amdgcn_s_barrier();
#pragma unroll
        for (int pass = 0; pass < 4; ++pass) {
          int row = (pass << 4) + rr;                          // 0..63
          u16x8 v = *(const u16x8*)(spare + (row << 8) + ((sl ^ (row & 7)) << 3));
          *(u16x8*)(dst + (size_t)(tile_m + (sw << 6) + row) * D_ + dbase + (sl << 3)) = v;
        }
        asm volatile("s_waitcnt lgkmcnt(0)" ::: "memory");
        __builtin_amdgcn_s_barrier();
      }
    } else {
      float* const Sf = (float*)spare;
      f4 bo = *(const f4*)(b_out + tile_n + (lane << 2));
#pragma unroll
      for (int sw = 0; sw < 8; ++sw) {
        if ((wm >> 7) == (sw >> 2)) {
          const int mb = (sw & 3) << 1;
#pragma unroll
          for (int mm = 0; mm < 2; ++mm) {
#pragma unroll
            for (int n = 0; n < 4; ++n)
#pragma unroll
              for (int r = 0; r < 4; ++r) {
                int lr = (mm << 4) + (lhi << 2) + r;           // 0..31 in sweep
                int lcol = wn + (n << 4) + l15;
                Sf[(lr << 8) + (((lcol >> 2) ^ (lr & 7)) << 2) + (lcol & 3)] = acc[mb + mm][n][r];
              }
          }
        }
        asm volatile("s_waitcnt lgkmcnt(0)" ::: "memory");
        __builtin_amdgcn_s_barrier();
#pragma unroll
        for (int pass = 0; pass < 4; ++pass) {
          int row = (pass << 3) + wave;                        // 0..31
          f4 v = *(const f4*)(Sf + (row << 8) + ((lane ^ (row & 7)) << 2));
          v[0] += bo[0]; v[1] += bo[1]; v[2] += bo[2]; v[3] += bo[3];
          *(f4*)(o_f + (size_t)(tile_m + (sw << 5) + row) * D_ + tile_n + (lane << 2)) = v;
        }
        asm volatile("s_waitcnt lgkmcnt(0)" ::: "memory");
        __builtin_amdgcn_s_barrier();
      }
    }

    // reset accumulators for the next tile
#pragma unroll
    for (int m = 0; m < 8; ++m)
#pragma unroll
      for (int n = 0; n < 4; ++n)
#pragma unroll
        for (int r = 0; r < 4; ++r) acc[m][n][r] = 0.0f;
  }
}

// ---------------- scan pass 1: per-chunk (prod-decay, zero-init state) ----------------
__global__ void k_scan1(const u16* __restrict__ dec, const u16* __restrict__ inp,
                        float* __restrict__ chA, float* __restrict__ chB) {
  int b = blockIdx.x / CCH, c = blockIdx.x % CCH;
  int d0 = threadIdx.x * 8;
  const u16* dp = dec + ((size_t)b * S_ + c * LCH) * D_ + d0;
  const u16* ip = inp + ((size_t)b * S_ + c * LCH) * D_ + d0;
  float Aa[8], st[8];
#pragma unroll
  for (int i = 0; i < 8; ++i) { Aa[i] = 1.0f; st[i] = 0.0f; }
#pragma unroll 4
  for (int j = 0; j < LCH; ++j) {
    u16x8 dv = *(const u16x8*)(dp + (size_t)j * D_);
    u16x8 iv = *(const u16x8*)(ip + (size_t)j * D_);
#pragma unroll
    for (int i = 0; i < 8; ++i) {
      float dd = bf2f(dv[i]), ii = bf2f(iv[i]);
      Aa[i] *= dd;
      st[i] = dd * st[i] + (1.0f - dd) * ii;
    }
  }
  size_t o = ((size_t)b * CCH + c) * D_ + d0;
#pragma unroll
  for (int i = 0; i < 8; ++i) { chA[o + i] = Aa[i]; chB[o + i] = st[i]; }
}

// ---------------- scan pass 2: sequential prefix over chunks (coalesced) ----------------
__global__ void k_scan2(const float* __restrict__ chA, const float* __restrict__ chB,
                        float* __restrict__ ini) {
  int b = blockIdx.x >> 3;
  int d = ((blockIdx.x & 7) << 8) + threadIdx.x;
  float st = 0.0f;
  for (int c = 0; c < CCH; ++c) {
    size_t o = ((size_t)b * CCH + c) * D_ + d;
    ini[o] = st;
    st = chA[o] * st + chB[o];
  }
}

// ---------------- scan pass 3: apply with true init, write y = gate*state ----------------
__global__ void k_scan3(const u16* __restrict__ dec, const u16* __restrict__ inp,
                        const u16* __restrict__ gat, const float* __restrict__ ini,
                        u16* __restrict__ y) {
  int b = blockIdx.x / CCH, c = blockIdx.x % CCH;
  int d0 = threadIdx.x * 8;
  size_t ib = ((size_t)b * CCH + c) * D_ + d0;
  float st[8];
#pragma unroll
  for (int i = 0; i < 8; ++i) st[i] = ini[ib + i];
  size_t base = ((size_t)b * S_ + c * LCH) * D_ + d0;
#pragma unroll 4
  for (int j = 0; j < LCH; ++j) {
    size_t o = base + (size_t)j * D_;
    u16x8 dv = *(const u16x8*)(dec + o);
    u16x8 iv = *(const u16x8*)(inp + o);
    u16x8 gv = *(const u16x8*)(gat + o);
    u16x8 yv;
#pragma unroll
    for (int i = 0; i < 8; ++i) {
      float dd = bf2f(dv[i]), ii = bf2f(iv[i]);
      st[i] = dd * st[i] + (1.0f - dd) * ii;
      yv[i] = f2bf(bf2f(gv[i]) * st[i]);
    }
    *(u16x8*)(y + o) = yv;
  }
}

extern "C" void kernel_launch(void* const* d_in, const int* in_sizes, int n_in,
                              void* d_out, int out_size, void* d_ws, size_t ws_size,
                              hipStream_t stream) {
  (void)in_sizes; (void)n_in; (void)out_size; (void)ws_size;
  const float* x      = (const float*)d_in[0];
  const float* W_in   = (const float*)d_in[1];
  const float* b_in   = (const float*)d_in[2];
  const float* W_dec  = (const float*)d_in[3];
  const float* b_dec  = (const float*)d_in[4];
  const float* W_gate = (const float*)d_in[5];
  const float* b_gate = (const float*)d_in[6];
  const float* W_out  = (const float*)d_in[7];
  const float* b_out  = (const float*)d_in[8];
  const float* dbias  = (const float*)d_in[9];
  float* out = (float*)d_out;

  char* ws = (char*)d_ws;
  u16*   xb  = (u16*)(ws);                    // 64 MiB (reused as y)
  u16*   w3t = (u16*)(ws + 67108864ull);      // 24 MiB
  u16*   wot = (u16*)(ws + 92274688ull);      //  8 MiB
  u16*   inp = (u16*)(ws + 100663296ull);     // 64 MiB
  u16*   dec = (u16*)(ws + 167772160ull);     // 64 MiB
  u16*   gat = (u16*)(ws + 234881024ull);     // 64 MiB
  float* chA = (float*)(ws + 301989888ull);
  float* chB = (float*)(ws + 306184192ull);
  float* ini = (float*)(ws + 310378496ull);
  u16*   y   = xb;

  hipFuncSetAttribute((const void*)k_gemm256,
                      hipFuncAttributeMaxDynamicSharedMemorySize, 163840);

  k_cvt<<<32768, 256, 0, stream>>>(x, xb, 8388608);
  k_tcvt<<<dim3(64, 64), 256, 0, stream>>>(W_in,   w3t);
  k_tcvt<<<dim3(64, 64), 256, 0, stream>>>(W_dec,  w3t + 2048 * 2048);
  k_tcvt<<<dim3(64, 64), 256, 0, stream>>>(W_gate, w3t + 2 * 2048 * 2048);
  k_tcvt<<<dim3(64, 64), 256, 0, stream>>>(W_out,  wot);

  k_gemm256<<<256, 512, 163840, stream>>>(
      xb, w3t, N3_, 0, 6, inp, dec, gat, b_in, b_dec, b_gate, dbias, nullptr, nullptr);

  k_scan1<<<B_ * CCH, 256, 0, stream>>>(dec, inp, chA, chB);
  k_scan2<<<32, 256, 0, stream>>>(chA, chB, ini);
  k_scan3<<<B_ * CCH, 256, 0, stream>>>(dec, inp, gat, ini, y);

  k_gemm256<<<256, 512, 163840, stream>>>(
      y, wot, D_, 1, 2, nullptr, nullptr, nullptr, nullptr, nullptr, nullptr, nullptr,
      out, b_out);
}

// Round 9
// 671.482 us; speedup vs baseline: 1.3791x; 1.3791x over previous
//
#include <hip/hip_runtime.h>

typedef unsigned short u16;
typedef __attribute__((ext_vector_type(4))) float f4;
typedef __attribute__((ext_vector_type(8))) short s8v;      // bf16x8 MFMA operand
typedef __attribute__((ext_vector_type(8))) unsigned short u16x8;
typedef __attribute__((ext_vector_type(4))) unsigned short u16x4;

#define B_   4
#define S_   4096
#define D_   2048
#define M_   (B_ * S_)     // 16384
#define K_   D_            // 2048
#define N3_  (3 * D_)      // 6144
#define CCH  128           // scan chunks
#define LCH  32            // chunk length
#define NTK  32            // K_ / 64 K-tiles

__device__ __forceinline__ u16 f2bf(float f) {
  unsigned u = __float_as_uint(f);
  u += 0x7FFF + ((u >> 16) & 1);   // RNE
  return (u16)(u >> 16);
}
__device__ __forceinline__ float bf2f(u16 h) {
  return __uint_as_float(((unsigned)h) << 16);
}
__device__ __forceinline__ float sigm(float z) {
  return 1.0f / (1.0f + __expf(-z));
}

// ---------------- fp32 -> bf16 elementwise (x) ----------------
__global__ void k_cvt(const float* __restrict__ src, u16* __restrict__ dst, int n4) {
  int i = blockIdx.x * 256 + threadIdx.x;
  if (i >= n4) return;
  f4 v = *(const f4*)(src + (size_t)i * 4);
  u16x4 o;
  o[0] = f2bf(v[0]); o[1] = f2bf(v[1]); o[2] = f2bf(v[2]); o[3] = f2bf(v[3]);
  *(u16x4*)(dst + (size_t)i * 4) = o;
}

// ---------------- fp32 [2048][2048] -> bf16 transpose ----------------
__global__ void k_tcvt(const float* __restrict__ src, u16* __restrict__ dst) {
  __shared__ float tile[32][33];
  int tx = threadIdx.x & 31, ty = threadIdx.x >> 5;
  int c0 = blockIdx.x * 32, r0 = blockIdx.y * 32;
#pragma unroll
  for (int j = 0; j < 32; j += 8)
    tile[ty + j][tx] = src[(size_t)(r0 + ty + j) * 2048 + c0 + tx];
  __syncthreads();
#pragma unroll
  for (int j = 0; j < 32; j += 8)
    dst[(size_t)(c0 + ty + j) * 2048 + r0 + tx] = f2bf(tile[tx][ty + j]);
}

// ---------------- 256x256 4-phase bf16 GEMM: A[M][K] @ (BT[N][K])^T ----------------
// 2 K-tiles per iteration, 4 phases: each phase = {stage 4 chunks, [vmcnt(6) at
// p1/p3], barrier, ds_read 2 quadrants (+B at p0/p2), 32 MFMA/wave, barrier}.
// Race-free ledger: a phase never stages a region read in the SAME phase; every
// staged chunk is >=7 loads old at the vmcnt(6) governing its reader (verified
// chunk-by-chunk). XOR slot swizzle s^(r&7) via pre-swizzled global source.
// XCD cluster map (R7): 32 co-resident tiles/XCD form a 4m x 8n window.
__global__ void __launch_bounds__(512, 2)
k_gemm256(const u16* __restrict__ A, const u16* __restrict__ BT, int N, int mode,
          u16* __restrict__ o_inp, u16* __restrict__ o_dec, u16* __restrict__ o_gate,
          const float* __restrict__ b_in, const float* __restrict__ b_dec,
          const float* __restrict__ b_gate, const float* __restrict__ dbias,
          float* __restrict__ o_f, const float* __restrict__ b_out) {
  extern __shared__ u16 smem[];
  u16* const Asb[2] = { smem,         smem + 16384 };
  u16* const Bsb[2] = { smem + 32768, smem + 49152 };

  // XCD cluster map: xcd = bid&7 owns m-bands 8*xcd..8*xcd+7.
  const int bid = blockIdx.x;
  const int xcd = bid & 7, j = bid >> 3;
  const int nsb = j >> 6;
  const int rj = j & 63;
  const int mm = rj >> 3, nn = rj & 7;
  const int tile_m = ((xcd << 3) + mm) << 8;
  const int tile_n = ((nsb << 3) + nn) << 8;

  const int tid = threadIdx.x;
  const int wave = tid >> 6, lane = tid & 63;
  const int wm = (wave >> 2) << 7;              // 0 or 128
  const int wn = (wave & 3) << 6;               // 0,64,128,192
  const int l15 = lane & 15, lhi = lane >> 4;
  const int srow = tid >> 3, sslot = tid & 7;   // staging: row-in-chunk, 16B slot

  f4 acc[8][4];
#pragma unroll
  for (int m = 0; m < 8; ++m)
#pragma unroll
    for (int n = 0; n < 4; ++n)
#pragma unroll
      for (int r = 0; r < 4; ++r) acc[m][n][r] = 0.0f;

  s8v bfr[2][4];   // B fragments [kk][n] — loaded at p0 (buf0) / p2 (buf1)

  auto STAGE = [&](const u16* __restrict__ G, int grow0, u16* L, int c, int k0) {
    int r = (c << 6) + srow;
    int sc = (sslot ^ (r & 7)) << 3;            // pre-swizzled source column
    __builtin_amdgcn_global_load_lds(
        (const __attribute__((address_space(1))) unsigned int*)(G + (size_t)(grow0 + r) * K_ + k0 + sc),
        (__attribute__((address_space(3))) unsigned int*)(L + (((c << 6) + (wave << 3)) << 6)),
        16, 0, 0);
  };

  auto RDB = [&](u16* Bb) {
#pragma unroll
    for (int kk = 0; kk < 2; ++kk)
#pragma unroll
      for (int n = 0; n < 4; ++n) {
        int r = wn + (n << 4) + l15;
        bfr[kk][n] = *(const s8v*)(Bb + (r << 6) + ((((kk << 2) + lhi) ^ (r & 7)) << 3));
      }
  };

  // read 2 quadrants (qbase, qbase+1) of A and run their 32 MFMAs
  auto RDMM = [&](u16* Ab, int qbase) {
    s8v a[2][2][2];   // [qi][mi][kk]
#pragma unroll
    for (int kk = 0; kk < 2; ++kk)
#pragma unroll
      for (int qi = 0; qi < 2; ++qi)
#pragma unroll
        for (int mi = 0; mi < 2; ++mi) {
          int r = wm + (((qbase + qi) * 2 + mi) << 4) + l15;
          a[qi][mi][kk] = *(const s8v*)(Ab + (r << 6) + ((((kk << 2) + lhi) ^ (r & 7)) << 3));
        }
    __builtin_amdgcn_s_setprio(1);
#pragma unroll
    for (int kk = 0; kk < 2; ++kk)
#pragma unroll
      for (int qi = 0; qi < 2; ++qi)
#pragma unroll
        for (int mi = 0; mi < 2; ++mi)
#pragma unroll
          for (int n = 0; n < 4; ++n)
            acc[(qbase + qi) * 2 + mi][n] =
                __builtin_amdgcn_mfma_f32_16x16x32_bf16(a[qi][mi][kk], bfr[kk][n],
                                                        acc[(qbase + qi) * 2 + mi][n], 0, 0, 0);
    __builtin_amdgcn_s_setprio(0);
  };

  // ---- prologue: buf0 = K-tile 0 (A+B), B-buf1 = K-tile 1 ----
#pragma unroll
  for (int c = 0; c < 4; ++c) STAGE(A, tile_m, Asb[0], c, 0);
#pragma unroll
  for (int c = 0; c < 4; ++c) STAGE(BT, tile_n, Bsb[0], c, 0);
#pragma unroll
  for (int c = 0; c < 4; ++c) STAGE(BT, tile_n, Bsb[1], c, 64);
  asm volatile("s_waitcnt vmcnt(4)" ::: "memory");   // buf0's 8 loads retired
  __builtin_amdgcn_s_barrier();

#pragma unroll 1
  for (int it = 0; it < NTK / 2; ++it) {
    const int t0 = it << 1;
    const int k1 = ((t0 + 1) & (NTK - 1)) << 6;
    const int k2 = ((t0 + 2) & (NTK - 1)) << 6;
    const int k3 = ((t0 + 3) & (NTK - 1)) << 6;

    // ---- p0: stage A-buf1 {0,2,1,3}@t0+1 ; read B-buf0 + A-buf0 q0,1 ----
    STAGE(A, tile_m, Asb[1], 0, k1); STAGE(A, tile_m, Asb[1], 2, k1);
    STAGE(A, tile_m, Asb[1], 1, k1); STAGE(A, tile_m, Asb[1], 3, k1);
    __builtin_amdgcn_s_barrier();
    RDB(Bsb[0]);
    RDMM(Asb[0], 0);
    __builtin_amdgcn_s_barrier();

    // ---- p1: stage B-buf0 @t0+2 ; vmcnt(6) ; read A-buf0 q2,3 ----
    STAGE(BT, tile_n, Bsb[0], 0, k2); STAGE(BT, tile_n, Bsb[0], 1, k2);
    STAGE(BT, tile_n, Bsb[0], 2, k2); STAGE(BT, tile_n, Bsb[0], 3, k2);
    asm volatile("s_waitcnt vmcnt(6)" ::: "memory");
    __builtin_amdgcn_sched_barrier(0);
    __builtin_amdgcn_s_barrier();
    RDMM(Asb[0], 2);
    __builtin_amdgcn_s_barrier();

    // ---- p2: stage A-buf0 {0,2,1,3}@t0+2 ; read B-buf1 + A-buf1 q0,1 ----
    STAGE(A, tile_m, Asb[0], 0, k2); STAGE(A, tile_m, Asb[0], 2, k2);
    STAGE(A, tile_m, Asb[0], 1, k2); STAGE(A, tile_m, Asb[0], 3, k2);
    __builtin_amdgcn_s_barrier();
    RDB(Bsb[1]);
    RDMM(Asb[1], 0);
    __builtin_amdgcn_s_barrier();

    // ---- p3: stage B-buf1 @t0+3 ; vmcnt(6) ; read A-buf1 q2,3 ----
    STAGE(BT, tile_n, Bsb[1], 0, k3); STAGE(BT, tile_n, Bsb[1], 1, k3);
    STAGE(BT, tile_n, Bsb[1], 2, k3); STAGE(BT, tile_n, Bsb[1], 3, k3);
    asm volatile("s_waitcnt vmcnt(6)" ::: "memory");
    __builtin_amdgcn_sched_barrier(0);
    __builtin_amdgcn_s_barrier();
    RDMM(Asb[1], 2);
    __builtin_amdgcn_s_barrier();
  }

  // ---- epilogue: drain in-flight gload_lds from ALL waves, then reuse LDS ----
  asm volatile("s_waitcnt vmcnt(0)" ::: "memory");
  __builtin_amdgcn_s_barrier();

  if (mode == 0) {
    const int selb = tile_n >> 11;
    const int dbase = tile_n & 2047;
    float bias[4];
#pragma unroll
    for (int n = 0; n < 4; ++n) {
      int d = dbase + wn + (n << 4) + l15;
      bias[n] = (selb == 0) ? b_in[d] : (selb == 1) ? (b_dec[d] + dbias[d]) : b_gate[d];
    }
#pragma unroll
    for (int m = 0; m < 8; ++m)
#pragma unroll
      for (int n = 0; n < 4; ++n)
#pragma unroll
        for (int r = 0; r < 4; ++r) {
          int lrow = wm + (m << 4) + (lhi << 2) + r;
          int lcol = wn + (n << 4) + l15;
          float z = acc[m][n][r] + bias[n];
          float v = (selb == 0) ? z * sigm(z) : sigm(z);
          smem[(lrow << 8) + (((lcol >> 3) ^ (lrow & 7)) << 3) + (lcol & 7)] = f2bf(v);
        }
    __builtin_amdgcn_s_barrier();
    u16* const dst = (selb == 0) ? o_inp : (selb == 1) ? o_dec : o_gate;
    const int rr = tid >> 5, sl = tid & 31;
#pragma unroll
    for (int pass = 0; pass < 16; ++pass) {
      int row = (pass << 4) + rr;
      u16x8 v = *(const u16x8*)(smem + (row << 8) + ((sl ^ (row & 7)) << 3));
      *(u16x8*)(dst + (size_t)(tile_m + row) * D_ + dbase + (sl << 3)) = v;
    }
  } else {
    float* const Tf = (float*)smem;
    f4 bo = *(const f4*)(b_out + tile_n + (lane << 2));
#pragma unroll
    for (int sw = 0; sw < 2; ++sw) {
      if (sw) __builtin_amdgcn_s_barrier();
      if ((wm >> 7) == sw) {
#pragma unroll
        for (int m = 0; m < 8; ++m)
#pragma unroll
          for (int n = 0; n < 4; ++n)
#pragma unroll
            for (int r = 0; r < 4; ++r) {
              int lrow = (m << 4) + (lhi << 2) + r;      // 0..127 within sweep
              int lcol = wn + (n << 4) + l15;
              Tf[(lrow << 8) + (((lcol >> 2) ^ (lrow & 7)) << 2) + (lcol & 3)] = acc[m][n][r];
            }
      }
      __builtin_amdgcn_s_barrier();
#pragma unroll
      for (int pass = 0; pass < 16; ++pass) {
        int lrow = (pass << 3) + wave;
        f4 v = *(const f4*)(Tf + (lrow << 8) + ((lane ^ (lrow & 7)) << 2));
        v[0] += bo[0]; v[1] += bo[1]; v[2] += bo[2]; v[3] += bo[3];
        *(f4*)(o_f + (size_t)(tile_m + (sw << 7) + lrow) * D_ + tile_n + (lane << 2)) = v;
      }
    }
  }
}

// ---------------- scan pass 1: per-chunk (prod-decay, zero-init state) ----------------
__global__ void k_scan1(const u16* __restrict__ dec, const u16* __restrict__ inp,
                        float* __restrict__ chA, float* __restrict__ chB) {
  int b = blockIdx.x / CCH, c = blockIdx.x % CCH;
  int d0 = threadIdx.x * 8;
  const u16* dp = dec + ((size_t)b * S_ + c * LCH) * D_ + d0;
  const u16* ip = inp + ((size_t)b * S_ + c * LCH) * D_ + d0;
  float Aa[8], st[8];
#pragma unroll
  for (int i = 0; i < 8; ++i) { Aa[i] = 1.0f; st[i] = 0.0f; }
#pragma unroll 4
  for (int j = 0; j < LCH; ++j) {
    u16x8 dv = *(const u16x8*)(dp + (size_t)j * D_);
    u16x8 iv = *(const u16x8*)(ip + (size_t)j * D_);
#pragma unroll
    for (int i = 0; i < 8; ++i) {
      float dd = bf2f(dv[i]), ii = bf2f(iv[i]);
      Aa[i] *= dd;
      st[i] = dd * st[i] + (1.0f - dd) * ii;
    }
  }
  size_t o = ((size_t)b * CCH + c) * D_ + d0;
#pragma unroll
  for (int i = 0; i < 8; ++i) { chA[o + i] = Aa[i]; chB[o + i] = st[i]; }
}

// ---------------- scan pass 2: sequential prefix over chunks (coalesced) ----------------
__global__ void k_scan2(const float* __restrict__ chA, const float* __restrict__ chB,
                        float* __restrict__ ini) {
  int b = blockIdx.x >> 3;
  int d = ((blockIdx.x & 7) << 8) + threadIdx.x;
  float st = 0.0f;
  for (int c = 0; c < CCH; ++c) {
    size_t o = ((size_t)b * CCH + c) * D_ + d;
    ini[o] = st;
    st = chA[o] * st + chB[o];
  }
}

// ---------------- scan pass 3: apply with true init, write y = gate*state ----------------
__global__ void k_scan3(const u16* __restrict__ dec, const u16* __restrict__ inp,
                        const u16* __restrict__ gat, const float* __restrict__ ini,
                        u16* __restrict__ y) {
  int b = blockIdx.x / CCH, c = blockIdx.x % CCH;
  int d0 = threadIdx.x * 8;
  size_t ib = ((size_t)b * CCH + c) * D_ + d0;
  float st[8];
#pragma unroll
  for (int i = 0; i < 8; ++i) st[i] = ini[ib + i];
  size_t base = ((size_t)b * S_ + c * LCH) * D_ + d0;
#pragma unroll 4
  for (int j = 0; j < LCH; ++j) {
    size_t o = base + (size_t)j * D_;
    u16x8 dv = *(const u16x8*)(dec + o);
    u16x8 iv = *(const u16x8*)(inp + o);
    u16x8 gv = *(const u16x8*)(gat + o);
    u16x8 yv;
#pragma unroll
    for (int i = 0; i < 8; ++i) {
      float dd = bf2f(dv[i]), ii = bf2f(iv[i]);
      st[i] = dd * st[i] + (1.0f - dd) * ii;
      yv[i] = f2bf(bf2f(gv[i]) * st[i]);
    }
    *(u16x8*)(y + o) = yv;
  }
}

extern "C" void kernel_launch(void* const* d_in, const int* in_sizes, int n_in,
                              void* d_out, int out_size, void* d_ws, size_t ws_size,
                              hipStream_t stream) {
  (void)in_sizes; (void)n_in; (void)out_size; (void)ws_size;
  const float* x      = (const float*)d_in[0];
  const float* W_in   = (const float*)d_in[1];
  const float* b_in   = (const float*)d_in[2];
  const float* W_dec  = (const float*)d_in[3];
  const float* b_dec  = (const float*)d_in[4];
  const float* W_gate = (const float*)d_in[5];
  const float* b_gate = (const float*)d_in[6];
  const float* W_out  = (const float*)d_in[7];
  const float* b_out  = (const float*)d_in[8];
  const float* dbias  = (const float*)d_in[9];
  float* out = (float*)d_out;

  char* ws = (char*)d_ws;
  u16*   xb  = (u16*)(ws);                    // 64 MiB (reused as y)
  u16*   w3t = (u16*)(ws + 67108864ull);      // 24 MiB
  u16*   wot = (u16*)(ws + 92274688ull);      //  8 MiB
  u16*   inp = (u16*)(ws + 100663296ull);     // 64 MiB
  u16*   dec = (u16*)(ws + 167772160ull);     // 64 MiB
  u16*   gat = (u16*)(ws + 234881024ull);     // 64 MiB
  float* chA = (float*)(ws + 301989888ull);
  float* chB = (float*)(ws + 306184192ull);
  float* ini = (float*)(ws + 310378496ull);
  u16*   y   = xb;

  hipFuncSetAttribute((const void*)k_gemm256,
                      hipFuncAttributeMaxDynamicSharedMemorySize, 131072);

  k_cvt<<<32768, 256, 0, stream>>>(x, xb, 8388608);
  k_tcvt<<<dim3(64, 64), 256, 0, stream>>>(W_in,   w3t);
  k_tcvt<<<dim3(64, 64), 256, 0, stream>>>(W_dec,  w3t + 2048 * 2048);
  k_tcvt<<<dim3(64, 64), 256, 0, stream>>>(W_gate, w3t + 2 * 2048 * 2048);
  k_tcvt<<<dim3(64, 64), 256, 0, stream>>>(W_out,  wot);

  k_gemm256<<<(M_ / 256) * (N3_ / 256), 512, 131072, stream>>>(
      xb, w3t, N3_, 0, inp, dec, gat, b_in, b_dec, b_gate, dbias, nullptr, nullptr);

  k_scan1<<<B_ * CCH, 256, 0, stream>>>(dec, inp, chA, chB);
  k_scan2<<<32, 256, 0, stream>>>(chA, chB, ini);
  k_scan3<<<B_ * CCH, 256, 0, stream>>>(dec, inp, gat, ini, y);

  k_gemm256<<<(M_ / 256) * (D_ / 256), 512, 131072, stream>>>(
      y, wot, D_, 1, nullptr, nullptr, nullptr, nullptr, nullptr, nullptr, nullptr,
      out, b_out);
}

// Round 10
// 651.878 us; speedup vs baseline: 1.4206x; 1.0301x over previous
//
#include <hip/hip_runtime.h>

typedef unsigned short u16;
typedef __attribute__((ext_vector_type(4))) float f4;
typedef __attribute__((ext_vector_type(8))) short s8v;      // bf16x8 MFMA operand
typedef __attribute__((ext_vector_type(8))) unsigned short u16x8;
typedef __attribute__((ext_vector_type(4))) unsigned short u16x4;

#define B_   4
#define S_   4096
#define D_   2048
#define M_   (B_ * S_)     // 16384
#define K_   D_            // 2048
#define N3_  (3 * D_)      // 6144
#define CCH  128           // scan chunks
#define LCH  32            // chunk length
#define NTK  32            // K_ / 64 K-tiles

__device__ __forceinline__ u16 f2bf(float f) {
  unsigned u = __float_as_uint(f);
  u += 0x7FFF + ((u >> 16) & 1);   // RNE
  return (u16)(u >> 16);
}
__device__ __forceinline__ float bf2f(u16 h) {
  return __uint_as_float(((unsigned)h) << 16);
}
__device__ __forceinline__ float sigm(float z) {
  return 1.0f / (1.0f + __expf(-z));
}

// ---------------- fp32 -> bf16 elementwise (x) ----------------
__global__ void k_cvt(const float* __restrict__ src, u16* __restrict__ dst, int n4) {
  int i = blockIdx.x * 256 + threadIdx.x;
  if (i >= n4) return;
  f4 v = *(const f4*)(src + (size_t)i * 4);
  u16x4 o;
  o[0] = f2bf(v[0]); o[1] = f2bf(v[1]); o[2] = f2bf(v[2]); o[3] = f2bf(v[3]);
  *(u16x4*)(dst + (size_t)i * 4) = o;
}

// ---------------- fp32 [2048][2048] -> bf16 transpose ----------------
__global__ void k_tcvt(const float* __restrict__ src, u16* __restrict__ dst) {
  __shared__ float tile[32][33];
  int tx = threadIdx.x & 31, ty = threadIdx.x >> 5;
  int c0 = blockIdx.x * 32, r0 = blockIdx.y * 32;
#pragma unroll
  for (int j = 0; j < 32; j += 8)
    tile[ty + j][tx] = src[(size_t)(r0 + ty + j) * 2048 + c0 + tx];
  __syncthreads();
#pragma unroll
  for (int j = 0; j < 32; j += 8)
    dst[(size_t)(c0 + ty + j) * 2048 + r0 + tx] = f2bf(tile[tx][ty + j]);
}

// ---------------- 256x256 8-phase bf16 GEMM (R7 structure + hoisted addrs) ---
// Identical schedule to the 653-us best (R7): 8 phases / 2 K-tiles, XOR slot
// swizzle s^(r&7) via pre-swizzled global source, A-fragments read-ahead one
// phase, B refreshed at q3 tails, vmcnt(6) at q3 only, XCD cluster map.
// NEW: all K-loop ds_read/staging addresses are loop-invariant lane pointers
// (r&7 == l15&7, row steps are 16 -> compile-time offset immediates), so the
// steady-state K-loop issues ~zero VALU (HK technique: prefilled swz offsets).
__global__ void __launch_bounds__(512, 2)
k_gemm256(const u16* __restrict__ A, const u16* __restrict__ BT, int N, int mode,
          u16* __restrict__ o_inp, u16* __restrict__ o_dec, u16* __restrict__ o_gate,
          const float* __restrict__ b_in, const float* __restrict__ b_dec,
          const float* __restrict__ b_gate, const float* __restrict__ dbias,
          float* __restrict__ o_f, const float* __restrict__ b_out) {
  extern __shared__ u16 smem[];
  u16* const Asb[2] = { smem,         smem + 16384 };
  u16* const Bsb[2] = { smem + 32768, smem + 49152 };

  // XCD cluster map: xcd = bid&7 owns m-bands 8*xcd..8*xcd+7.
  const int bid = blockIdx.x;
  const int xcd = bid & 7, j = bid >> 3;
  const int nsb = j >> 6;
  const int rj = j & 63;
  const int mm = rj >> 3, nn = rj & 7;
  const int tile_m = ((xcd << 3) + mm) << 8;
  const int tile_n = ((nsb << 3) + nn) << 8;

  const int tid = threadIdx.x;
  const int wave = tid >> 6, lane = tid & 63;
  const int wm = (wave >> 2) << 7;              // 0 or 128
  const int wn = (wave & 3) << 6;               // 0,64,128,192
  const int l15 = lane & 15, lhi = lane >> 4;
  const int srow = tid >> 3, sslot = tid & 7;   // staging: row-in-chunk, 16B slot

  f4 acc[8][4];
#pragma unroll
  for (int m = 0; m < 8; ++m)
#pragma unroll
    for (int n = 0; n < 4; ++n)
#pragma unroll
      for (int r = 0; r < 4; ++r) acc[m][n][r] = 0.0f;

  s8v afr2[2][2][2];   // A fragments [set][mi][kk]
  s8v bfr[2][4];       // B fragments [kk][n]

  // ---- loop-invariant lane pointers (indices compile-time under unroll) ----
  const int swz = l15 & 7;
  const u16* ap[2][2];   // [buf][kk], q=0/mi=0 base; quadrant/mi step = 16 rows = 1<<10 elems
  const u16* bp[2][2];   // [buf][kk], n=0 base; n step = 1<<10 elems
#pragma unroll
  for (int b = 0; b < 2; ++b)
#pragma unroll
    for (int kk = 0; kk < 2; ++kk) {
      const int so = ((((kk << 2) + lhi) ^ swz) << 3);
      ap[b][kk] = Asb[b] + ((wm + l15) << 6) + so;
      bp[b][kk] = Bsb[b] + ((wn + l15) << 6) + so;
    }
  // staging: per-lane global element offset (c-invariant since r&7 = srow&7)
  const int gl = srow * K_ + ((sslot ^ (srow & 7)) << 3);

  auto STAGE = [&](const u16* __restrict__ G, int grow0, u16* L, int c, int k0) {
    const u16* src = G + (size_t)(grow0 + (c << 6)) * K_ + k0;   // uniform (saddr)
    __builtin_amdgcn_global_load_lds(
        (const __attribute__((address_space(1))) unsigned int*)(src + gl),
        (__attribute__((address_space(3))) unsigned int*)(L + (((c << 6) + (wave << 3)) << 6)),
        16, 0, 0);
  };

  // ---- prologue: tile 0 fully (8 chunks) + tile 1 partial (B all, A chunks 0,2)
#pragma unroll
  for (int c = 0; c < 4; ++c) STAGE(A, tile_m, Asb[0], c, 0);
#pragma unroll
  for (int c = 0; c < 4; ++c) STAGE(BT, tile_n, Bsb[0], c, 0);
#pragma unroll
  for (int c = 0; c < 4; ++c) STAGE(BT, tile_n, Bsb[1], c, 64);
  STAGE(A, tile_m, Asb[1], 0, 64);
  STAGE(A, tile_m, Asb[1], 2, 64);
  asm volatile("s_waitcnt vmcnt(6)" ::: "memory");   // tile 0's 8 loads retired
  __builtin_amdgcn_s_barrier();

  // ---- prologue register fill: phase-0 operands (A q0 set0 + B, buffer 0)
#pragma unroll
  for (int kk = 0; kk < 2; ++kk)
#pragma unroll
    for (int mi = 0; mi < 2; ++mi)
      afr2[0][mi][kk] = *(const s8v*)(ap[0][kk] + (mi << 10));
#pragma unroll
  for (int kk = 0; kk < 2; ++kk)
#pragma unroll
    for (int n = 0; n < 4; ++n)
      bfr[kk][n] = *(const s8v*)(bp[0][kk] + (n << 10));

#pragma unroll 1
  for (int it = 0; it < NTK / 2; ++it) {
    const int t0 = it << 1;
#pragma unroll
    for (int p = 0; p < 8; ++p) {
      const int toff[8] = {1, 2, 2, 2, 2, 3, 3, 3};   // staged tile = t0 + toff
      const int sopA[8] = {1, 0, 0, 1, 1, 0, 0, 1};   // 1 = stage A chunks, 0 = B
      const int sc0[8]  = {1, 0, 2, 0, 1, 0, 2, 0};
      const int sc1f[8] = {3, 1, 3, 2, 3, 1, 3, 2};
      const int q = p & 3;

      // ---- stage: 2 chunks of a future tile into long-consumed regions ----
      {
        const int st = (t0 + toff[p]) & (NTK - 1);   // wraps harmlessly on last iter
        const int k0s = st << 6;
        u16* const Ad = Asb[st & 1];
        u16* const Bd = Bsb[st & 1];
        if (sopA[p]) { STAGE(A, tile_m, Ad, sc0[p], k0s); STAGE(A, tile_m, Ad, sc1f[p], k0s); }
        else         { STAGE(BT, tile_n, Bd, sc0[p], k0s); STAGE(BT, tile_n, Bd, sc1f[p], k0s); }
      }
      if (q == 3) {
        asm volatile("s_waitcnt vmcnt(6)" ::: "memory");  // next buf's 8 loads landed
        __builtin_amdgcn_sched_barrier(0);
      }
      __builtin_amdgcn_s_barrier();

      // ---- read-ahead: A fragments for phase p+1 (drains under this MFMA) ----
      {
        const int pn = p + 1;
        const int qn = pn & 3, bn = (pn >> 2) & 1, as = pn & 1;
#pragma unroll
        for (int kk = 0; kk < 2; ++kk)
#pragma unroll
          for (int mi = 0; mi < 2; ++mi)
            afr2[as][mi][kk] = *(const s8v*)(ap[bn][kk] + (((qn << 1) + mi) << 10));
      }

      __builtin_amdgcn_s_setprio(1);
#pragma unroll
      for (int kk = 0; kk < 2; ++kk)
#pragma unroll
        for (int mi = 0; mi < 2; ++mi)
#pragma unroll
          for (int n = 0; n < 4; ++n)
            acc[q * 2 + mi][n] =
                __builtin_amdgcn_mfma_f32_16x16x32_bf16(afr2[p & 1][mi][kk], bfr[kk][n],
                                                        acc[q * 2 + mi][n], 0, 0, 0);
      __builtin_amdgcn_s_setprio(0);

      // ---- q3 tail: refresh B fragments for the next 4 phases ----
      if (q == 3) {
        const int bn = ((p + 1) >> 2) & 1;
#pragma unroll
        for (int kk = 0; kk < 2; ++kk)
#pragma unroll
          for (int n = 0; n < 4; ++n)
            bfr[kk][n] = *(const s8v*)(bp[bn][kk] + (n << 10));
      }
      __builtin_amdgcn_s_barrier();
    }
  }

  // ---- epilogue: drain in-flight gload_lds from ALL waves, then reuse LDS ----
  asm volatile("s_waitcnt vmcnt(0)" ::: "memory");
  __builtin_amdgcn_s_barrier();

  if (mode == 0) {
    const int selb = tile_n >> 11;
    const int dbase = tile_n & 2047;
    float bias[4];
#pragma unroll
    for (int n = 0; n < 4; ++n) {
      int d = dbase + wn + (n << 4) + l15;
      bias[n] = (selb == 0) ? b_in[d] : (selb == 1) ? (b_dec[d] + dbias[d]) : b_gate[d];
    }
#pragma unroll
    for (int m = 0; m < 8; ++m)
#pragma unroll
      for (int n = 0; n < 4; ++n)
#pragma unroll
        for (int r = 0; r < 4; ++r) {
          int lrow = wm + (m << 4) + (lhi << 2) + r;
          int lcol = wn + (n << 4) + l15;
          float z = acc[m][n][r] + bias[n];
          float v = (selb == 0) ? z * sigm(z) : sigm(z);
          smem[(lrow << 8) + (((lcol >> 3) ^ (lrow & 7)) << 3) + (lcol & 7)] = f2bf(v);
        }
    __builtin_amdgcn_s_barrier();
    u16* const dst = (selb == 0) ? o_inp : (selb == 1) ? o_dec : o_gate;
    const int rr = tid >> 5, sl = tid & 31;
#pragma unroll
    for (int pass = 0; pass < 16; ++pass) {
      int row = (pass << 4) + rr;
      u16x8 v = *(const u16x8*)(smem + (row << 8) + ((sl ^ (row & 7)) << 3));
      *(u16x8*)(dst + (size_t)(tile_m + row) * D_ + dbase + (sl << 3)) = v;
    }
  } else {
    float* const Tf = (float*)smem;
    f4 bo = *(const f4*)(b_out + tile_n + (lane << 2));
#pragma unroll
    for (int sw = 0; sw < 2; ++sw) {
      if (sw) __builtin_amdgcn_s_barrier();
      if ((wm >> 7) == sw) {
#pragma unroll
        for (int m = 0; m < 8; ++m)
#pragma unroll
          for (int n = 0; n < 4; ++n)
#pragma unroll
            for (int r = 0; r < 4; ++r) {
              int lrow = (m << 4) + (lhi << 2) + r;      // 0..127 within sweep
              int lcol = wn + (n << 4) + l15;
              Tf[(lrow << 8) + (((lcol >> 2) ^ (lrow & 7)) << 2) + (lcol & 3)] = acc[m][n][r];
            }
      }
      __builtin_amdgcn_s_barrier();
#pragma unroll
      for (int pass = 0; pass < 16; ++pass) {
        int lrow = (pass << 3) + wave;
        f4 v = *(const f4*)(Tf + (lrow << 8) + ((lane ^ (lrow & 7)) << 2));
        v[0] += bo[0]; v[1] += bo[1]; v[2] += bo[2]; v[3] += bo[3];
        *(f4*)(o_f + (size_t)(tile_m + (sw << 7) + lrow) * D_ + tile_n + (lane << 2)) = v;
      }
    }
  }
}

// ---------------- scan pass 1: per-chunk (prod-decay, zero-init state) ----------------
__global__ void k_scan1(const u16* __restrict__ dec, const u16* __restrict__ inp,
                        float* __restrict__ chA, float* __restrict__ chB) {
  int b = blockIdx.x / CCH, c = blockIdx.x % CCH;
  int d0 = threadIdx.x * 8;
  const u16* dp = dec + ((size_t)b * S_ + c * LCH) * D_ + d0;
  const u16* ip = inp + ((size_t)b * S_ + c * LCH) * D_ + d0;
  float Aa[8], st[8];
#pragma unroll
  for (int i = 0; i < 8; ++i) { Aa[i] = 1.0f; st[i] = 0.0f; }
#pragma unroll 4
  for (int j = 0; j < LCH; ++j) {
    u16x8 dv = *(const u16x8*)(dp + (size_t)j * D_);
    u16x8 iv = *(const u16x8*)(ip + (size_t)j * D_);
#pragma unroll
    for (int i = 0; i < 8; ++i) {
      float dd = bf2f(dv[i]), ii = bf2f(iv[i]);
      Aa[i] *= dd;
      st[i] = dd * st[i] + (1.0f - dd) * ii;
    }
  }
  size_t o = ((size_t)b * CCH + c) * D_ + d0;
#pragma unroll
  for (int i = 0; i < 8; ++i) { chA[o + i] = Aa[i]; chB[o + i] = st[i]; }
}

// ---------------- scan pass 2: sequential prefix over chunks (coalesced) ----------------
__global__ void k_scan2(const float* __restrict__ chA, const float* __restrict__ chB,
                        float* __restrict__ ini) {
  int b = blockIdx.x >> 3;
  int d = ((blockIdx.x & 7) << 8) + threadIdx.x;
  float st = 0.0f;
  for (int c = 0; c < CCH; ++c) {
    size_t o = ((size_t)b * CCH + c) * D_ + d;
    ini[o] = st;
    st = chA[o] * st + chB[o];
  }
}

// ---------------- scan pass 3: apply with true init, write y = gate*state ----------------
__global__ void k_scan3(const u16* __restrict__ dec, const u16* __restrict__ inp,
                        const u16* __restrict__ gat, const float* __restrict__ ini,
                        u16* __restrict__ y) {
  int b = blockIdx.x / CCH, c = blockIdx.x % CCH;
  int d0 = threadIdx.x * 8;
  size_t ib = ((size_t)b * CCH + c) * D_ + d0;
  float st[8];
#pragma unroll
  for (int i = 0; i < 8; ++i) st[i] = ini[ib + i];
  size_t base = ((size_t)b * S_ + c * LCH) * D_ + d0;
#pragma unroll 4
  for (int j = 0; j < LCH; ++j) {
    size_t o = base + (size_t)j * D_;
    u16x8 dv = *(const u16x8*)(dec + o);
    u16x8 iv = *(const u16x8*)(inp + o);
    u16x8 gv = *(const u16x8*)(gat + o);
    u16x8 yv;
#pragma unroll
    for (int i = 0; i < 8; ++i) {
      float dd = bf2f(dv[i]), ii = bf2f(iv[i]);
      st[i] = dd * st[i] + (1.0f - dd) * ii;
      yv[i] = f2bf(bf2f(gv[i]) * st[i]);
    }
    *(u16x8*)(y + o) = yv;
  }
}

extern "C" void kernel_launch(void* const* d_in, const int* in_sizes, int n_in,
                              void* d_out, int out_size, void* d_ws, size_t ws_size,
                              hipStream_t stream) {
  (void)in_sizes; (void)n_in; (void)out_size; (void)ws_size;
  const float* x      = (const float*)d_in[0];
  const float* W_in   = (const float*)d_in[1];
  const float* b_in   = (const float*)d_in[2];
  const float* W_dec  = (const float*)d_in[3];
  const float* b_dec  = (const float*)d_in[4];
  const float* W_gate = (const float*)d_in[5];
  const float* b_gate = (const float*)d_in[6];
  const float* W_out  = (const float*)d_in[7];
  const float* b_out  = (const float*)d_in[8];
  const float* dbias  = (const float*)d_in[9];
  float* out = (float*)d_out;

  char* ws = (char*)d_ws;
  u16*   xb  = (u16*)(ws);                    // 64 MiB (reused as y)
  u16*   w3t = (u16*)(ws + 67108864ull);      // 24 MiB
  u16*   wot = (u16*)(ws + 92274688ull);      //  8 MiB
  u16*   inp = (u16*)(ws + 100663296ull);     // 64 MiB
  u16*   dec = (u16*)(ws + 167772160ull);     // 64 MiB
  u16*   gat = (u16*)(ws + 234881024ull);     // 64 MiB
  float* chA = (float*)(ws + 301989888ull);
  float* chB = (float*)(ws + 306184192ull);
  float* ini = (float*)(ws + 310378496ull);
  u16*   y   = xb;

  hipFuncSetAttribute((const void*)k_gemm256,
                      hipFuncAttributeMaxDynamicSharedMemorySize, 131072);

  k_cvt<<<32768, 256, 0, stream>>>(x, xb, 8388608);
  k_tcvt<<<dim3(64, 64), 256, 0, stream>>>(W_in,   w3t);
  k_tcvt<<<dim3(64, 64), 256, 0, stream>>>(W_dec,  w3t + 2048 * 2048);
  k_tcvt<<<dim3(64, 64), 256, 0, stream>>>(W_gate, w3t + 2 * 2048 * 2048);
  k_tcvt<<<dim3(64, 64), 256, 0, stream>>>(W_out,  wot);

  k_gemm256<<<(M_ / 256) * (N3_ / 256), 512, 131072, stream>>>(
      xb, w3t, N3_, 0, inp, dec, gat, b_in, b_dec, b_gate, dbias, nullptr, nullptr);

  k_scan1<<<B_ * CCH, 256, 0, stream>>>(dec, inp, chA, chB);
  k_scan2<<<32, 256, 0, stream>>>(chA, chB, ini);
  k_scan3<<<B_ * CCH, 256, 0, stream>>>(dec, inp, gat, ini, y);

  k_gemm256<<<(M_ / 256) * (D_ / 256), 512, 131072, stream>>>(
      y, wot, D_, 1, nullptr, nullptr, nullptr, nullptr, nullptr, nullptr, nullptr,
      out, b_out);
}